// Round 1
// baseline (544.341 us; speedup 1.0000x reference)
//
#include <hip/hip_runtime.h>

#define N_NODES 100000
#define F_IN 128
#define F_HID 32

// ---------------- degree + norm ----------------

__global__ void degree_kernel(const int* __restrict__ src, const int* __restrict__ dst,
                              int* __restrict__ deg_out, int* __restrict__ deg_in, int E) {
    int e = blockIdx.x * blockDim.x + threadIdx.x;
    if (e < E) {
        atomicAdd(&deg_out[src[e]], 1);
        atomicAdd(&deg_in[dst[e]], 1);
    }
}

__global__ void norm_kernel(const int* __restrict__ deg_out, const int* __restrict__ deg_in,
                            float* __restrict__ norm_out, float* __restrict__ norm_in, int n) {
    int i = blockIdx.x * blockDim.x + threadIdx.x;
    if (i < n) {
        float a = (float)(deg_out[i] > 1 ? deg_out[i] : 1);
        float b = (float)(deg_in[i]  > 1 ? deg_in[i]  : 1);
        norm_out[i] = rsqrtf(a);
        norm_in[i]  = rsqrtf(b);
    }
}

// ---------------- projections ----------------

// h[n,32] = x[n,128] @ W[128,32]; one node per thread, W staged in LDS.
__global__ void gemm1_kernel(const float* __restrict__ x, const float* __restrict__ W,
                             float* __restrict__ h, int n) {
    __shared__ float Wl[F_IN * F_HID];  // 16 KB
    for (int i = threadIdx.x; i < F_IN * F_HID; i += blockDim.x) Wl[i] = W[i];
    __syncthreads();
    int node = blockIdx.x * blockDim.x + threadIdx.x;
    if (node >= n) return;
    float acc[F_HID];
#pragma unroll
    for (int j = 0; j < F_HID; ++j) acc[j] = 0.f;
    const float4* row = reinterpret_cast<const float4*>(x + (size_t)node * F_IN);
#pragma unroll 2
    for (int k4 = 0; k4 < F_IN / 4; ++k4) {
        float4 v = row[k4];
        const float* w0 = &Wl[(k4 * 4 + 0) * F_HID];
        const float* w1 = &Wl[(k4 * 4 + 1) * F_HID];
        const float* w2 = &Wl[(k4 * 4 + 2) * F_HID];
        const float* w3 = &Wl[(k4 * 4 + 3) * F_HID];
#pragma unroll
        for (int j = 0; j < F_HID; ++j)
            acc[j] += v.x * w0[j] + v.y * w1[j] + v.z * w2[j] + v.w * w3[j];
    }
    float* out = h + (size_t)node * F_HID;
#pragma unroll
    for (int j = 0; j < F_HID; ++j) out[j] = acc[j];
}

// h2[n,32] = h[n,32] @ W[32,32]
__global__ void gemm2_kernel(const float* __restrict__ h, const float* __restrict__ W,
                             float* __restrict__ h2, int n) {
    __shared__ float Wl[F_HID * F_HID];  // 4 KB
    for (int i = threadIdx.x; i < F_HID * F_HID; i += blockDim.x) Wl[i] = W[i];
    __syncthreads();
    int node = blockIdx.x * blockDim.x + threadIdx.x;
    if (node >= n) return;
    float acc[F_HID];
#pragma unroll
    for (int j = 0; j < F_HID; ++j) acc[j] = 0.f;
    const float4* row = reinterpret_cast<const float4*>(h + (size_t)node * F_HID);
#pragma unroll
    for (int k4 = 0; k4 < F_HID / 4; ++k4) {
        float4 v = row[k4];
        const float* w0 = &Wl[(k4 * 4 + 0) * F_HID];
        const float* w1 = &Wl[(k4 * 4 + 1) * F_HID];
        const float* w2 = &Wl[(k4 * 4 + 2) * F_HID];
        const float* w3 = &Wl[(k4 * 4 + 3) * F_HID];
#pragma unroll
        for (int j = 0; j < F_HID; ++j)
            acc[j] += v.x * w0[j] + v.y * w1[j] + v.z * w2[j] + v.w * w3[j];
    }
    float* out = h2 + (size_t)node * F_HID;
#pragma unroll
    for (int j = 0; j < F_HID; ++j) out[j] = acc[j];
}

// ---------------- edge aggregation ----------------

// agg[dst] += h[src] * norm_src[src]; 32 lanes per edge (one per feature).
__global__ void edge_agg_kernel(const float* __restrict__ h, const int* __restrict__ src,
                                const int* __restrict__ dst, const float* __restrict__ norm_src,
                                float* __restrict__ agg, int E) {
    long long idx = (long long)blockIdx.x * blockDim.x + threadIdx.x;
    int e = (int)(idx >> 5);
    int f = (int)(idx & 31);
    if (e < E) {
        int s = src[e];
        int d = dst[e];
        float v = h[(size_t)s * F_HID + f] * norm_src[s];
        atomicAdd(&agg[(size_t)d * F_HID + f], v);
    }
}

// ---------------- epilogues ----------------

__global__ void relu_bias_kernel(float* __restrict__ agg, const float* __restrict__ norm_in,
                                 const float* __restrict__ b, int n) {
    int i = blockIdx.x * blockDim.x + threadIdx.x;
    if (i < n * F_HID) {
        int node = i >> 5;
        int f = i & 31;
        float v = agg[i] * norm_in[node] + b[f];
        agg[i] = v > 0.f ? v : 0.f;
    }
}

__global__ void bias_kernel(float* __restrict__ agg, const float* __restrict__ norm_in,
                            const float* __restrict__ b, int n) {
    int i = blockIdx.x * blockDim.x + threadIdx.x;
    if (i < n * F_HID) {
        int node = i >> 5;
        int f = i & 31;
        agg[i] = agg[i] * norm_in[node] + b[f];
    }
}

// ---------------- launch ----------------

static inline size_t align256(size_t x) { return (x + 255) & ~(size_t)255; }

extern "C" void kernel_launch(void* const* d_in, const int* in_sizes, int n_in,
                              void* d_out, int out_size, void* d_ws, size_t ws_size,
                              hipStream_t stream) {
    const float* features = (const float*)d_in[0];
    const float* W1 = (const float*)d_in[1];
    const float* b1 = (const float*)d_in[2];
    const float* W2 = (const float*)d_in[3];
    const float* b2 = (const float*)d_in[4];
    const int* src = (const int*)d_in[5];
    const int* dst = (const int*)d_in[6];
    const int E = in_sizes[5];
    const int n = N_NODES;

    char* ws = (char*)d_ws;
    size_t off = 0;
    int* deg_out = (int*)(ws + off);   off += align256((size_t)n * 4);
    int* deg_in = (int*)(ws + off);    off += align256((size_t)n * 4);
    float* norm_out = (float*)(ws + off); off += align256((size_t)n * 4);
    float* norm_in = (float*)(ws + off);  off += align256((size_t)n * 4);
    float* bufA = (float*)(ws + off);  off += align256((size_t)n * F_HID * 4);
    float* bufB = (float*)(ws + off);  off += align256((size_t)n * F_HID * 4);
    float* out = (float*)d_out;

    // zero accumulators
    hipMemsetAsync(deg_out, 0, (size_t)n * 4, stream);
    hipMemsetAsync(deg_in, 0, (size_t)n * 4, stream);
    hipMemsetAsync(bufB, 0, (size_t)n * F_HID * 4, stream);
    hipMemsetAsync(out, 0, (size_t)n * F_HID * 4, stream);

    // degrees + norms
    degree_kernel<<<(E + 255) / 256, 256, 0, stream>>>(src, dst, deg_out, deg_in, E);
    norm_kernel<<<(n + 255) / 256, 256, 0, stream>>>(deg_out, deg_in, norm_out, norm_in, n);

    // layer 1: project, aggregate, relu+bias
    gemm1_kernel<<<(n + 255) / 256, 256, 0, stream>>>(features, W1, bufA, n);
    {
        long long total = (long long)E * F_HID;
        int blocks = (int)((total + 255) / 256);
        edge_agg_kernel<<<blocks, 256, 0, stream>>>(bufA, src, dst, norm_out, bufB, E);
    }
    relu_bias_kernel<<<(n * F_HID + 255) / 256, 256, 0, stream>>>(bufB, norm_in, b1, n);

    // layer 2: project, aggregate, bias
    gemm2_kernel<<<(n + 255) / 256, 256, 0, stream>>>(bufB, W2, bufA, n);
    {
        long long total = (long long)E * F_HID;
        int blocks = (int)((total + 255) / 256);
        edge_agg_kernel<<<blocks, 256, 0, stream>>>(bufA, src, dst, norm_out, out, E);
    }
    bias_kernel<<<(n * F_HID + 255) / 256, 256, 0, stream>>>(out, norm_in, b2, n);
}

// Round 2
// 399.715 us; speedup vs baseline: 1.3618x; 1.3618x over previous
//
#include <hip/hip_runtime.h>

#define N_NODES 100000
#define F_IN 128
#define F_HID 32

// ---------------- degree + norm ----------------

__global__ void degree_kernel(const int* __restrict__ src, const int* __restrict__ dst,
                              int* __restrict__ deg_out, int* __restrict__ deg_in, int E) {
    int e = blockIdx.x * blockDim.x + threadIdx.x;
    if (e < E) {
        atomicAdd(&deg_out[src[e]], 1);
        atomicAdd(&deg_in[dst[e]], 1);
    }
}

__global__ void norm_kernel(const int* __restrict__ deg_out, const int* __restrict__ deg_in,
                            float* __restrict__ norm_out, float* __restrict__ norm_in, int n) {
    int i = blockIdx.x * blockDim.x + threadIdx.x;
    if (i < n) {
        float a = (float)(deg_out[i] > 1 ? deg_out[i] : 1);
        float b = (float)(deg_in[i]  > 1 ? deg_in[i]  : 1);
        norm_out[i] = rsqrtf(a);
        norm_in[i]  = rsqrtf(b);
    }
}

// ---------------- CSR build: scan + scatter ----------------

__global__ void scan_block_reduce(const int* __restrict__ deg, int* __restrict__ bsum, int n) {
    __shared__ int s[256];
    int i = blockIdx.x * 256 + threadIdx.x;
    s[threadIdx.x] = (i < n) ? deg[i] : 0;
    __syncthreads();
    for (int stride = 128; stride > 0; stride >>= 1) {
        if (threadIdx.x < stride) s[threadIdx.x] += s[threadIdx.x + stride];
        __syncthreads();
    }
    if (threadIdx.x == 0) bsum[blockIdx.x] = s[0];
}

// single block, 512 threads, nb <= 512
__global__ void scan_bsums(const int* __restrict__ bsum, int* __restrict__ bscan, int nb) {
    __shared__ int buf[2][512];
    int t = threadIdx.x;
    buf[0][t] = (t < nb) ? bsum[t] : 0;
    __syncthreads();
    int cur = 0;
    for (int off = 1; off < 512; off <<= 1) {
        int v = buf[cur][t];
        if (t >= off) v += buf[cur][t - off];
        buf[cur ^ 1][t] = v;
        cur ^= 1;
        __syncthreads();
    }
    if (t < nb) bscan[t] = (t == 0) ? 0 : buf[cur][t - 1];
}

__global__ void scan_final(const int* __restrict__ deg, const int* __restrict__ bscan,
                           int* __restrict__ row_ptr, int n) {
    __shared__ int buf[2][256];
    int t = threadIdx.x;
    int i = blockIdx.x * 256 + t;
    int v = (i < n) ? deg[i] : 0;
    buf[0][t] = v;
    __syncthreads();
    int cur = 0;
    for (int off = 1; off < 256; off <<= 1) {
        int x = buf[cur][t];
        if (t >= off) x += buf[cur][t - off];
        buf[cur ^ 1][t] = x;
        cur ^= 1;
        __syncthreads();
    }
    if (i < n) row_ptr[i] = bscan[blockIdx.x] + buf[cur][t] - v;  // exclusive
}

__global__ void scatter_kernel(const int* __restrict__ src, const int* __restrict__ dst,
                               const int* __restrict__ row_ptr, int* __restrict__ cnt,
                               int* __restrict__ col, int E) {
    int e = blockIdx.x * blockDim.x + threadIdx.x;
    if (e < E) {
        int d = dst[e];
        int pos = atomicAdd(&cnt[d], 1);
        col[row_ptr[d] + pos] = src[e];
    }
}

// ---------------- projection (layer 1) with norm_out prescale ----------------

// h1s[node] = (x[node] @ W1) * norm_out[node]
__global__ void gemm1_kernel(const float* __restrict__ x, const float* __restrict__ W,
                             const float* __restrict__ norm_out, float* __restrict__ h, int n) {
    __shared__ float Wl[F_IN * F_HID];  // 16 KB
    for (int i = threadIdx.x; i < F_IN * F_HID; i += blockDim.x) Wl[i] = W[i];
    __syncthreads();
    int node = blockIdx.x * blockDim.x + threadIdx.x;
    if (node >= n) return;
    float acc[F_HID];
#pragma unroll
    for (int j = 0; j < F_HID; ++j) acc[j] = 0.f;
    const float4* row = reinterpret_cast<const float4*>(x + (size_t)node * F_IN);
#pragma unroll 2
    for (int k4 = 0; k4 < F_IN / 4; ++k4) {
        float4 v = row[k4];
        const float* w0 = &Wl[(k4 * 4 + 0) * F_HID];
        const float* w1 = &Wl[(k4 * 4 + 1) * F_HID];
        const float* w2 = &Wl[(k4 * 4 + 2) * F_HID];
        const float* w3 = &Wl[(k4 * 4 + 3) * F_HID];
#pragma unroll
        for (int j = 0; j < F_HID; ++j)
            acc[j] += v.x * w0[j] + v.y * w1[j] + v.z * w2[j] + v.w * w3[j];
    }
    float s = norm_out[node];
    float* out = h + (size_t)node * F_HID;
#pragma unroll
    for (int j = 0; j < F_HID; ++j) out[j] = acc[j] * s;
}

// ---------------- fused aggregation kernels ----------------

// layer-1 aggregate + relu+bias+norm_in, then GEMM2 via shuffles, prescale norm_out.
// 32 lanes per node (one per feature).
__global__ void agg1_kernel(const float* __restrict__ h1s, const int* __restrict__ row_ptr,
                            const int* __restrict__ deg_in, const int* __restrict__ col,
                            const float* __restrict__ norm_in, const float* __restrict__ norm_out,
                            const float* __restrict__ b1, const float* __restrict__ W2,
                            float* __restrict__ h2s, int n) {
    __shared__ float W2l[F_HID * F_HID];
    for (int i = threadIdx.x; i < F_HID * F_HID; i += blockDim.x) W2l[i] = W2[i];
    __syncthreads();
    int lane = threadIdx.x & 31;
    int node = blockIdx.x * (blockDim.x >> 5) + (threadIdx.x >> 5);
    if (node >= n) return;
    int start = row_ptr[node];
    int deg = deg_in[node];
    float acc0 = 0.f, acc1 = 0.f;
    int j = 0;
    for (; j + 1 < deg; j += 2) {
        int s0 = col[start + j];
        int s1 = col[start + j + 1];
        acc0 += h1s[(size_t)s0 * F_HID + lane];
        acc1 += h1s[(size_t)s1 * F_HID + lane];
    }
    if (j < deg) acc0 += h1s[(size_t)col[start + j] * F_HID + lane];
    float t = (acc0 + acc1) * norm_in[node] + b1[lane];
    t = t > 0.f ? t : 0.f;
    // GEMM2: o[lane] = sum_k t[k] * W2[k][lane]
    float o = 0.f;
#pragma unroll
    for (int k = 0; k < F_HID; ++k) {
        float tk = __shfl(t, k, 32);
        o += tk * W2l[k * F_HID + lane];
    }
    h2s[(size_t)node * F_HID + lane] = o * norm_out[node];
}

// layer-2 aggregate + bias+norm_in -> final output
__global__ void agg2_kernel(const float* __restrict__ h2s, const int* __restrict__ row_ptr,
                            const int* __restrict__ deg_in, const int* __restrict__ col,
                            const float* __restrict__ norm_in, const float* __restrict__ b2,
                            float* __restrict__ out, int n) {
    int lane = threadIdx.x & 31;
    int node = blockIdx.x * (blockDim.x >> 5) + (threadIdx.x >> 5);
    if (node >= n) return;
    int start = row_ptr[node];
    int deg = deg_in[node];
    float acc0 = 0.f, acc1 = 0.f;
    int j = 0;
    for (; j + 1 < deg; j += 2) {
        int s0 = col[start + j];
        int s1 = col[start + j + 1];
        acc0 += h2s[(size_t)s0 * F_HID + lane];
        acc1 += h2s[(size_t)s1 * F_HID + lane];
    }
    if (j < deg) acc0 += h2s[(size_t)col[start + j] * F_HID + lane];
    out[(size_t)node * F_HID + lane] = (acc0 + acc1) * norm_in[node] + b2[lane];
}

// ---------------- launch ----------------

static inline size_t align256(size_t x) { return (x + 255) & ~(size_t)255; }

extern "C" void kernel_launch(void* const* d_in, const int* in_sizes, int n_in,
                              void* d_out, int out_size, void* d_ws, size_t ws_size,
                              hipStream_t stream) {
    const float* features = (const float*)d_in[0];
    const float* W1 = (const float*)d_in[1];
    const float* b1 = (const float*)d_in[2];
    const float* W2 = (const float*)d_in[3];
    const float* b2 = (const float*)d_in[4];
    const int* src = (const int*)d_in[5];
    const int* dst = (const int*)d_in[6];
    const int E = in_sizes[5];
    const int n = N_NODES;
    const int NB = (n + 255) / 256;  // 391 <= 512

    char* ws = (char*)d_ws;
    size_t off = 0;
    int* deg_in = (int*)(ws + off);       off += align256((size_t)n * 4);
    int* deg_out = (int*)(ws + off);      off += align256((size_t)n * 4);  // reused as cnt
    float* norm_out = (float*)(ws + off); off += align256((size_t)n * 4);
    float* norm_in = (float*)(ws + off);  off += align256((size_t)n * 4);
    int* row_ptr = (int*)(ws + off);      off += align256((size_t)n * 4);
    int* bsum = (int*)(ws + off);         off += align256(512 * 4);
    int* bscan = (int*)(ws + off);        off += align256(512 * 4);
    int* col = (int*)(ws + off);          off += align256((size_t)E * 4);
    float* h1s = (float*)(ws + off);      off += align256((size_t)n * F_HID * 4);
    float* h2s = (float*)(ws + off);      off += align256((size_t)n * F_HID * 4);
    float* out = (float*)d_out;

    hipMemsetAsync(deg_in, 0, (size_t)n * 4, stream);
    hipMemsetAsync(deg_out, 0, (size_t)n * 4, stream);

    degree_kernel<<<(E + 255) / 256, 256, 0, stream>>>(src, dst, deg_out, deg_in, E);
    norm_kernel<<<NB, 256, 0, stream>>>(deg_out, deg_in, norm_out, norm_in, n);

    // CSR over dst
    scan_block_reduce<<<NB, 256, 0, stream>>>(deg_in, bsum, n);
    scan_bsums<<<1, 512, 0, stream>>>(bsum, bscan, NB);
    scan_final<<<NB, 256, 0, stream>>>(deg_in, bscan, row_ptr, n);
    int* cnt = deg_out;  // deg_out dead after norm_kernel
    hipMemsetAsync(cnt, 0, (size_t)n * 4, stream);
    scatter_kernel<<<(E + 255) / 256, 256, 0, stream>>>(src, dst, row_ptr, cnt, col, E);

    // layer 1 projection (+ norm_out prescale)
    gemm1_kernel<<<NB, 256, 0, stream>>>(features, W1, norm_out, h1s, n);

    // layer-1 aggregate + relu/bias + GEMM2 + prescale  (8 nodes per 256-thread block)
    agg1_kernel<<<(n + 7) / 8, 256, 0, stream>>>(h1s, row_ptr, deg_in, col, norm_in,
                                                 norm_out, b1, W2, h2s, n);
    // layer-2 aggregate + bias -> out
    agg2_kernel<<<(n + 7) / 8, 256, 0, stream>>>(h2s, row_ptr, deg_in, col, norm_in, b2, out, n);
}